// Round 12
// baseline (797.333 us; speedup 1.0000x reference)
//
#include <hip/hip_runtime.h>

// GCN, 2-layer: N=100000 nodes, E=3.2M edges, F=512 -> H=16 -> 16 -> 1.
// NOTE: harness stages integer inputs as int32 ("integer -> const int*").
// edge_index is therefore int32 [2, E] flattened: rows at ei[0..E), cols at
// ei[E..2E). Casting to int64 caused an OOB read -> GPU fault (rounds 8/10).
// Two paths selected by ws_size: CSR gather path (~27.2 MB) or atomic
// scatter fallback (~13.6 MB). All data-derived indices bounds-guarded.

#define NTHREADS 256

// ---------- degree histogram ----------
__global__ void hist_kernel(const int* __restrict__ col, int E, int n,
                            int* __restrict__ indeg) {
    int i = blockIdx.x * blockDim.x + threadIdx.x;
    int stride = gridDim.x * blockDim.x;
    for (; i < E; i += stride) {
        int c = col[i];
        if ((unsigned)c < (unsigned)n) atomicAdd(&indeg[c], 1);
    }
}

// ---------- dinv = rsqrt(indeg + 1)  (self-loop included) ----------
__global__ void dinv_kernel(const int* __restrict__ indeg,
                            float* __restrict__ dinv, int n) {
    int v = blockIdx.x * blockDim.x + threadIdx.x;
    if (v < n) dinv[v] = rsqrtf((float)(indeg[v] + 1));
}

// ---------- exclusive scan of indeg -> rowptr (3 small kernels) ----------
__global__ void scan_block_sums(const int* __restrict__ indeg,
                                int* __restrict__ partial, int n) {
    __shared__ int s[NTHREADS];
    int t = threadIdx.x, i = blockIdx.x * NTHREADS + t;
    s[t] = (i < n) ? indeg[i] : 0;
    __syncthreads();
    for (int off = NTHREADS / 2; off > 0; off >>= 1) {
        if (t < off) s[t] += s[t + off];
        __syncthreads();
    }
    if (t == 0) partial[blockIdx.x] = s[0];
}

__global__ void scan_partials(int* __restrict__ partial, int nb,
                              int* __restrict__ rowptr, int n, int E) {
    __shared__ int s[512];
    int t = threadIdx.x;
    int v = (t < nb) ? partial[t] : 0;
    s[t] = v;
    __syncthreads();
    for (int off = 1; off < 512; off <<= 1) {
        int add = (t >= off) ? s[t - off] : 0;
        __syncthreads();
        s[t] += add;
        __syncthreads();
    }
    if (t < nb) partial[t] = s[t] - v;   // exclusive prefix of block sums
    if (t == 0) rowptr[n] = E;
}

__global__ void scan_write(const int* __restrict__ indeg,
                           const int* __restrict__ partial,
                           int* __restrict__ rowptr, int n) {
    __shared__ int s[NTHREADS];
    int t = threadIdx.x, i = blockIdx.x * NTHREADS + t;
    int v = (i < n) ? indeg[i] : 0;
    s[t] = v;
    __syncthreads();
    for (int off = 1; off < NTHREADS; off <<= 1) {
        int add = (t >= off) ? s[t - off] : 0;
        __syncthreads();
        s[t] += add;
        __syncthreads();
    }
    if (i < n) rowptr[i] = partial[blockIdx.x] + s[t] - v;  // exclusive
}

// ---------- fill CSR adjacency (by destination) ----------
__global__ void fill_kernel(const int* __restrict__ ei, int E, int n,
                            const int* __restrict__ rowptr,
                            int* __restrict__ cnt, int* __restrict__ adj) {
    int i = blockIdx.x * blockDim.x + threadIdx.x;
    int stride = gridDim.x * blockDim.x;
    for (; i < E; i += stride) {
        int r = ei[i];
        int c = ei[E + i];
        if ((unsigned)r >= (unsigned)n || (unsigned)c >= (unsigned)n) continue;
        int pos = rowptr[c] + atomicAdd(&cnt[c], 1);
        adj[pos] = r;
    }
}

// ---------- hs1 = (x @ W1) * dinv[v] : thread per row, W1 wave-uniform ----------
__global__ void gemm1_kernel(const float* __restrict__ x,
                             const float* __restrict__ W1,
                             const float* __restrict__ dinv,
                             float* __restrict__ hs1, int n) {
    int v = blockIdx.x * blockDim.x + threadIdx.x;
    if (v >= n) return;
    const float4* xr = (const float4*)(x + (size_t)v * 512);
    float acc[16];
#pragma unroll
    for (int h = 0; h < 16; ++h) acc[h] = 0.f;
#pragma unroll 4
    for (int k4 = 0; k4 < 128; ++k4) {
        float4 xv = xr[k4];                 // 16B/lane; line reuse via L1
        const float* wr = W1 + k4 * 64;     // wave-uniform -> s_load
#pragma unroll
        for (int i = 0; i < 4; ++i) {
            float xs = (&xv.x)[i];
#pragma unroll
            for (int h = 0; h < 16; ++h)
                acc[h] = fmaf(xs, wr[i * 16 + h], acc[h]);
        }
    }
    float d = dinv[v];
    float4* o = (float4*)(hs1 + (size_t)v * 16);
#pragma unroll
    for (int q = 0; q < 4; ++q)
        o[q] = make_float4(acc[4 * q] * d, acc[4 * q + 1] * d,
                           acc[4 * q + 2] * d, acc[4 * q + 3] * d);
}

// ========== CSR-path aggregation kernels ==========
__global__ void agg1_kernel(const float* __restrict__ hs1,
                            const int* __restrict__ rowptr,
                            const int* __restrict__ adj,
                            const float* __restrict__ dinv,
                            const float* __restrict__ b1,
                            const float* __restrict__ W2,
                            float* __restrict__ hs2, int n) {
    __shared__ float w2s[256];
    int t = threadIdx.x;
    w2s[t] = W2[t];
    __syncthreads();
    int g = t >> 4, j = t & 15;
    int v = blockIdx.x * 16 + g;
    if (v >= n) return;
    int beg = rowptr[v], end = rowptr[v + 1];
    float acc = hs1[(size_t)v * 16 + j];            // self loop
    for (int i = beg; i < end; ++i) {
        int u = adj[i];
        acc += hs1[(size_t)u * 16 + j];
    }
    float d = dinv[v];
    float val = fmaxf(fmaf(d, acc, b1[j]), 0.f);    // relu(out1)
    float o = 0.f;
#pragma unroll
    for (int jj = 0; jj < 16; ++jj) {
        float bc = __shfl(val, (t & ~15) | jj);
        o = fmaf(bc, w2s[jj * 16 + j], o);
    }
    hs2[(size_t)v * 16 + j] = o * d;
}

__global__ void agg2_kernel(const float* __restrict__ hs2,
                            const int* __restrict__ rowptr,
                            const int* __restrict__ adj,
                            const float* __restrict__ dinv,
                            const float* __restrict__ b2,
                            const float* __restrict__ Wl,
                            const float* __restrict__ bl,
                            float* __restrict__ out, int n) {
    int t = threadIdx.x;
    int g = t >> 4, j = t & 15;
    int v = blockIdx.x * 16 + g;
    if (v >= n) return;
    int beg = rowptr[v], end = rowptr[v + 1];
    float acc = hs2[(size_t)v * 16 + j];            // self loop
    for (int i = beg; i < end; ++i) {
        acc += hs2[(size_t)adj[i] * 16 + j];
    }
    float d = dinv[v];
    float val = fmaxf(fmaf(d, acc, b2[j]), 0.f);
    float p = val * Wl[j];
#pragma unroll
    for (int off = 8; off > 0; off >>= 1)
        p += __shfl_down(p, off, 16);
    if (j == 0) out[v] = p + bl[0];
}

// ========== Atomic-path kernels (low-workspace fallback) ==========
// dst must be pre-seeded with the self-loop term (d2d copy of src).
__global__ void scatter16_kernel(const float* __restrict__ src,
                                 float* __restrict__ dst,
                                 const int* __restrict__ ei,
                                 int E, int n) {
    int total = E * 16;
    int i = blockIdx.x * blockDim.x + threadIdx.x;
    int stride = gridDim.x * blockDim.x;
    for (; i < total; i += stride) {
        int e = i >> 4, j = i & 15;
        int u = ei[e];
        int v = ei[E + e];
        if ((unsigned)u < (unsigned)n && (unsigned)v < (unsigned)n)
            atomicAdd(&dst[(size_t)v * 16 + j], src[(size_t)u * 16 + j]);
    }
}

// in-place: hs2[v] = dinv[v] * (relu(dinv[v]*hs2[v] + b1) @ W2)
__global__ void xform1_kernel(float* __restrict__ hs2,
                              const float* __restrict__ dinv,
                              const float* __restrict__ b1,
                              const float* __restrict__ W2, int n) {
    __shared__ float w2s[256];
    int t = threadIdx.x;
    w2s[t] = W2[t];
    __syncthreads();
    int g = t >> 4, j = t & 15;
    int v = blockIdx.x * 16 + g;
    if (v >= n) return;
    float d = dinv[v];
    float val = fmaxf(fmaf(d, hs2[(size_t)v * 16 + j], b1[j]), 0.f);
    float o = 0.f;
#pragma unroll
    for (int jj = 0; jj < 16; ++jj) {
        float bc = __shfl(val, (t & ~15) | jj);
        o = fmaf(bc, w2s[jj * 16 + j], o);
    }
    hs2[(size_t)v * 16 + j] = o * d;
}

// out[v] = relu(dinv[v]*hs1[v] + b2) @ Wl + bl
__global__ void xform2_kernel(const float* __restrict__ hs1,
                              const float* __restrict__ dinv,
                              const float* __restrict__ b2,
                              const float* __restrict__ Wl,
                              const float* __restrict__ bl,
                              float* __restrict__ out, int n) {
    int t = threadIdx.x;
    int g = t >> 4, j = t & 15;
    int v = blockIdx.x * 16 + g;
    if (v >= n) return;
    float d = dinv[v];
    float val = fmaxf(fmaf(d, hs1[(size_t)v * 16 + j], b2[j]), 0.f);
    float p = val * Wl[j];
#pragma unroll
    for (int off = 8; off > 0; off >>= 1)
        p += __shfl_down(p, off, 16);
    if (j == 0) out[v] = p + bl[0];
}

extern "C" void kernel_launch(void* const* d_in, const int* in_sizes, int n_in,
                              void* d_out, int out_size, void* d_ws, size_t ws_size,
                              hipStream_t stream) {
    const float* x  = (const float*)d_in[0];
    const int*   ei = (const int*)d_in[1];   // int32 [2, E] (harness stages int as int32)
    const float* W1 = (const float*)d_in[2];
    const float* b1 = (const float*)d_in[3];
    const float* W2 = (const float*)d_in[4];
    const float* b2 = (const float*)d_in[5];
    const float* Wl = (const float*)d_in[6];
    const float* bl = (const float*)d_in[7];
    float* out = (float*)d_out;

    const int n = in_sizes[0] / 512;   // 100000
    const int E = in_sizes[1] / 2;     // 3200000

    char* ws = (char*)d_ws;
    size_t off = 0;
    auto alloc = [&](size_t bytes) {
        void* p = ws + off;
        off += (bytes + 255) & ~(size_t)255;
        return p;
    };

    const size_t sz_n4  = (size_t)n * 4;
    const size_t sz_hs  = (size_t)n * 16 * 4;
    // CSR layout total: 4*~n4 + 4096 + E*4 + 2*hs  ~= 27.21 MB
    const size_t REQ_CSR =
        4 * ((sz_n4 + 255 + 4) & ~(size_t)255) + 4096 +
        ((size_t)E * 4) + 2 * sz_hs + 4096;

    const int nb = (n + NTHREADS - 1) / NTHREADS;  // 391 (fits scan_partials' 512)
    const int nodeblocks = (n + 15) / 16;

    if (ws_size == 0 || ws_size >= REQ_CSR) {
        // ---------------- CSR path ----------------
        int*   indeg   = (int*)alloc(sz_n4);
        int*   cnt     = (int*)alloc(sz_n4);
        float* dinv    = (float*)alloc(sz_n4);
        int*   rowptr  = (int*)alloc(sz_n4 + 4);
        int*   partial = (int*)alloc(4096);
        int*   adj     = (int*)alloc((size_t)E * 4);
        float* hs1     = (float*)alloc(sz_hs);
        float* hs2     = (float*)alloc(sz_hs);

        hipMemsetAsync(indeg, 0, sz_n4, stream);
        hipMemsetAsync(cnt, 0, sz_n4, stream);

        hist_kernel<<<1024, NTHREADS, 0, stream>>>(ei + E, E, n, indeg);
        dinv_kernel<<<nb, NTHREADS, 0, stream>>>(indeg, dinv, n);
        scan_block_sums<<<nb, NTHREADS, 0, stream>>>(indeg, partial, n);
        scan_partials<<<1, 512, 0, stream>>>(partial, nb, rowptr, n, E);
        scan_write<<<nb, NTHREADS, 0, stream>>>(indeg, partial, rowptr, n);
        fill_kernel<<<2048, NTHREADS, 0, stream>>>(ei, E, n, rowptr, cnt, adj);

        gemm1_kernel<<<nb, NTHREADS, 0, stream>>>(x, W1, dinv, hs1, n);
        agg1_kernel<<<nodeblocks, NTHREADS, 0, stream>>>(hs1, rowptr, adj, dinv,
                                                         b1, W2, hs2, n);
        agg2_kernel<<<nodeblocks, NTHREADS, 0, stream>>>(hs2, rowptr, adj, dinv,
                                                         b2, Wl, bl, out, n);
    } else {
        // ---------------- Atomic fallback path (~13.6 MB) ----------------
        int*   indeg = (int*)alloc(sz_n4);
        float* dinv  = (float*)alloc(sz_n4);
        float* hs1   = (float*)alloc(sz_hs);
        float* hs2   = (float*)alloc(sz_hs);

        hipMemsetAsync(indeg, 0, sz_n4, stream);
        hist_kernel<<<1024, NTHREADS, 0, stream>>>(ei + E, E, n, indeg);
        dinv_kernel<<<nb, NTHREADS, 0, stream>>>(indeg, dinv, n);

        gemm1_kernel<<<nb, NTHREADS, 0, stream>>>(x, W1, dinv, hs1, n);

        // layer 1: seed self-loop, scatter, transform in place
        hipMemcpyAsync(hs2, hs1, sz_hs, hipMemcpyDeviceToDevice, stream);
        scatter16_kernel<<<4096, NTHREADS, 0, stream>>>(hs1, hs2, ei, E, n);
        xform1_kernel<<<nodeblocks, NTHREADS, 0, stream>>>(hs2, dinv, b1, W2, n);

        // layer 2: seed, scatter, project
        hipMemcpyAsync(hs1, hs2, sz_hs, hipMemcpyDeviceToDevice, stream);
        scatter16_kernel<<<4096, NTHREADS, 0, stream>>>(hs2, hs1, ei, E, n);
        xform2_kernel<<<nodeblocks, NTHREADS, 0, stream>>>(hs1, dinv, b2, Wl,
                                                           bl, out, n);
    }
}

// Round 14
// 765.982 us; speedup vs baseline: 1.0409x; 1.0409x over previous
//
#include <hip/hip_runtime.h>

// GCN, 2-layer: N=100000 nodes, E=3.2M edges, F=512 -> H=16 -> 16 -> 1.
// edge_index is int32 [2, E]: rows at ei[0..E), cols at ei[E..2E).
// CSR gather path (ws >= ~27.2 MB) or atomic scatter fallback.
// R13: fill grid 4x + nontemporal adj store (WRITE_SIZE showed 64B/4B
// amplification, latency-bound at 18% HBM); hist grid 4x; agg gather
// 4-way unrolled (break serial acc chain, 4 loads in flight).

#define NTHREADS 256

// ---------- degree histogram ----------
__global__ void hist_kernel(const int* __restrict__ col, int E, int n,
                            int* __restrict__ indeg) {
    int i = blockIdx.x * blockDim.x + threadIdx.x;
    int stride = gridDim.x * blockDim.x;
    for (; i < E; i += stride) {
        int c = col[i];
        if ((unsigned)c < (unsigned)n) atomicAdd(&indeg[c], 1);
    }
}

// ---------- dinv = rsqrt(indeg + 1)  (self-loop included) ----------
__global__ void dinv_kernel(const int* __restrict__ indeg,
                            float* __restrict__ dinv, int n) {
    int v = blockIdx.x * blockDim.x + threadIdx.x;
    if (v < n) dinv[v] = rsqrtf((float)(indeg[v] + 1));
}

// ---------- exclusive scan of indeg -> rowptr (3 small kernels) ----------
__global__ void scan_block_sums(const int* __restrict__ indeg,
                                int* __restrict__ partial, int n) {
    __shared__ int s[NTHREADS];
    int t = threadIdx.x, i = blockIdx.x * NTHREADS + t;
    s[t] = (i < n) ? indeg[i] : 0;
    __syncthreads();
    for (int off = NTHREADS / 2; off > 0; off >>= 1) {
        if (t < off) s[t] += s[t + off];
        __syncthreads();
    }
    if (t == 0) partial[blockIdx.x] = s[0];
}

__global__ void scan_partials(int* __restrict__ partial, int nb,
                              int* __restrict__ rowptr, int n, int E) {
    __shared__ int s[512];
    int t = threadIdx.x;
    int v = (t < nb) ? partial[t] : 0;
    s[t] = v;
    __syncthreads();
    for (int off = 1; off < 512; off <<= 1) {
        int add = (t >= off) ? s[t - off] : 0;
        __syncthreads();
        s[t] += add;
        __syncthreads();
    }
    if (t < nb) partial[t] = s[t] - v;   // exclusive prefix of block sums
    if (t == 0) rowptr[n] = E;
}

__global__ void scan_write(const int* __restrict__ indeg,
                           const int* __restrict__ partial,
                           int* __restrict__ rowptr, int n) {
    __shared__ int s[NTHREADS];
    int t = threadIdx.x, i = blockIdx.x * NTHREADS + t;
    int v = (i < n) ? indeg[i] : 0;
    s[t] = v;
    __syncthreads();
    for (int off = 1; off < NTHREADS; off <<= 1) {
        int add = (t >= off) ? s[t - off] : 0;
        __syncthreads();
        s[t] += add;
        __syncthreads();
    }
    if (i < n) rowptr[i] = partial[blockIdx.x] + s[t] - v;  // exclusive
}

// ---------- fill CSR adjacency (by destination) ----------
__global__ void fill_kernel(const int* __restrict__ ei, int E, int n,
                            const int* __restrict__ rowptr,
                            int* __restrict__ cnt, int* __restrict__ adj) {
    int i = blockIdx.x * blockDim.x + threadIdx.x;
    int stride = gridDim.x * blockDim.x;
    for (; i < E; i += stride) {
        int r = ei[i];
        int c = ei[E + i];
        if ((unsigned)r >= (unsigned)n || (unsigned)c >= (unsigned)n) continue;
        int pos = rowptr[c] + atomicAdd(&cnt[c], 1);
        __builtin_nontemporal_store(r, &adj[pos]);
    }
}

// ---------- hs1 = (x @ W1) * dinv[v] : thread per row, W1 wave-uniform ----------
__global__ void gemm1_kernel(const float* __restrict__ x,
                             const float* __restrict__ W1,
                             const float* __restrict__ dinv,
                             float* __restrict__ hs1, int n) {
    int v = blockIdx.x * blockDim.x + threadIdx.x;
    if (v >= n) return;
    const float4* xr = (const float4*)(x + (size_t)v * 512);
    float acc[16];
#pragma unroll
    for (int h = 0; h < 16; ++h) acc[h] = 0.f;
#pragma unroll 4
    for (int k4 = 0; k4 < 128; ++k4) {
        float4 xv = xr[k4];                 // 16B/lane; line reuse via L1
        const float* wr = W1 + k4 * 64;     // wave-uniform -> s_load
#pragma unroll
        for (int i = 0; i < 4; ++i) {
            float xs = (&xv.x)[i];
#pragma unroll
            for (int h = 0; h < 16; ++h)
                acc[h] = fmaf(xs, wr[i * 16 + h], acc[h]);
        }
    }
    float d = dinv[v];
    float4* o = (float4*)(hs1 + (size_t)v * 16);
#pragma unroll
    for (int q = 0; q < 4; ++q)
        o[q] = make_float4(acc[4 * q] * d, acc[4 * q + 1] * d,
                           acc[4 * q + 2] * d, acc[4 * q + 3] * d);
}

// ========== CSR-path aggregation kernels ==========
// 16 lanes per node; 4-way unrolled gather for memory-level parallelism.
__global__ void agg1_kernel(const float* __restrict__ hs1,
                            const int* __restrict__ rowptr,
                            const int* __restrict__ adj,
                            const float* __restrict__ dinv,
                            const float* __restrict__ b1,
                            const float* __restrict__ W2,
                            float* __restrict__ hs2, int n) {
    __shared__ float w2s[256];
    int t = threadIdx.x;
    w2s[t] = W2[t];
    __syncthreads();
    int g = t >> 4, j = t & 15;
    int v = blockIdx.x * 16 + g;
    if (v >= n) return;
    int beg = rowptr[v], end = rowptr[v + 1];
    float acc = hs1[(size_t)v * 16 + j];            // self loop
    float a0 = 0.f, a1 = 0.f, a2 = 0.f, a3 = 0.f;
    int i = beg;
    for (; i + 4 <= end; i += 4) {
        int u0 = adj[i], u1 = adj[i + 1], u2 = adj[i + 2], u3 = adj[i + 3];
        a0 += hs1[(size_t)u0 * 16 + j];
        a1 += hs1[(size_t)u1 * 16 + j];
        a2 += hs1[(size_t)u2 * 16 + j];
        a3 += hs1[(size_t)u3 * 16 + j];
    }
    for (; i < end; ++i) acc += hs1[(size_t)adj[i] * 16 + j];
    acc += (a0 + a1) + (a2 + a3);
    float d = dinv[v];
    float val = fmaxf(fmaf(d, acc, b1[j]), 0.f);    // relu(out1)
    float o = 0.f;
#pragma unroll
    for (int jj = 0; jj < 16; ++jj) {
        float bc = __shfl(val, (t & ~15) | jj);
        o = fmaf(bc, w2s[jj * 16 + j], o);
    }
    hs2[(size_t)v * 16 + j] = o * d;
}

__global__ void agg2_kernel(const float* __restrict__ hs2,
                            const int* __restrict__ rowptr,
                            const int* __restrict__ adj,
                            const float* __restrict__ dinv,
                            const float* __restrict__ b2,
                            const float* __restrict__ Wl,
                            const float* __restrict__ bl,
                            float* __restrict__ out, int n) {
    int t = threadIdx.x;
    int g = t >> 4, j = t & 15;
    int v = blockIdx.x * 16 + g;
    if (v >= n) return;
    int beg = rowptr[v], end = rowptr[v + 1];
    float acc = hs2[(size_t)v * 16 + j];            // self loop
    float a0 = 0.f, a1 = 0.f, a2 = 0.f, a3 = 0.f;
    int i = beg;
    for (; i + 4 <= end; i += 4) {
        int u0 = adj[i], u1 = adj[i + 1], u2 = adj[i + 2], u3 = adj[i + 3];
        a0 += hs2[(size_t)u0 * 16 + j];
        a1 += hs2[(size_t)u1 * 16 + j];
        a2 += hs2[(size_t)u2 * 16 + j];
        a3 += hs2[(size_t)u3 * 16 + j];
    }
    for (; i < end; ++i) acc += hs2[(size_t)adj[i] * 16 + j];
    acc += (a0 + a1) + (a2 + a3);
    float d = dinv[v];
    float val = fmaxf(fmaf(d, acc, b2[j]), 0.f);
    float p = val * Wl[j];
#pragma unroll
    for (int off = 8; off > 0; off >>= 1)
        p += __shfl_down(p, off, 16);
    if (j == 0) out[v] = p + bl[0];
}

// ========== Atomic-path kernels (low-workspace fallback) ==========
__global__ void scatter16_kernel(const float* __restrict__ src,
                                 float* __restrict__ dst,
                                 const int* __restrict__ ei,
                                 int E, int n) {
    int total = E * 16;
    int i = blockIdx.x * blockDim.x + threadIdx.x;
    int stride = gridDim.x * blockDim.x;
    for (; i < total; i += stride) {
        int e = i >> 4, j = i & 15;
        int u = ei[e];
        int v = ei[E + e];
        if ((unsigned)u < (unsigned)n && (unsigned)v < (unsigned)n)
            atomicAdd(&dst[(size_t)v * 16 + j], src[(size_t)u * 16 + j]);
    }
}

__global__ void xform1_kernel(float* __restrict__ hs2,
                              const float* __restrict__ dinv,
                              const float* __restrict__ b1,
                              const float* __restrict__ W2, int n) {
    __shared__ float w2s[256];
    int t = threadIdx.x;
    w2s[t] = W2[t];
    __syncthreads();
    int g = t >> 4, j = t & 15;
    int v = blockIdx.x * 16 + g;
    if (v >= n) return;
    float d = dinv[v];
    float val = fmaxf(fmaf(d, hs2[(size_t)v * 16 + j], b1[j]), 0.f);
    float o = 0.f;
#pragma unroll
    for (int jj = 0; jj < 16; ++jj) {
        float bc = __shfl(val, (t & ~15) | jj);
        o = fmaf(bc, w2s[jj * 16 + j], o);
    }
    hs2[(size_t)v * 16 + j] = o * d;
}

__global__ void xform2_kernel(const float* __restrict__ hs1,
                              const float* __restrict__ dinv,
                              const float* __restrict__ b2,
                              const float* __restrict__ Wl,
                              const float* __restrict__ bl,
                              float* __restrict__ out, int n) {
    int t = threadIdx.x;
    int g = t >> 4, j = t & 15;
    int v = blockIdx.x * 16 + g;
    if (v >= n) return;
    float d = dinv[v];
    float val = fmaxf(fmaf(d, hs1[(size_t)v * 16 + j], b2[j]), 0.f);
    float p = val * Wl[j];
#pragma unroll
    for (int off = 8; off > 0; off >>= 1)
        p += __shfl_down(p, off, 16);
    if (j == 0) out[v] = p + bl[0];
}

extern "C" void kernel_launch(void* const* d_in, const int* in_sizes, int n_in,
                              void* d_out, int out_size, void* d_ws, size_t ws_size,
                              hipStream_t stream) {
    const float* x  = (const float*)d_in[0];
    const int*   ei = (const int*)d_in[1];   // int32 [2, E]
    const float* W1 = (const float*)d_in[2];
    const float* b1 = (const float*)d_in[3];
    const float* W2 = (const float*)d_in[4];
    const float* b2 = (const float*)d_in[5];
    const float* Wl = (const float*)d_in[6];
    const float* bl = (const float*)d_in[7];
    float* out = (float*)d_out;

    const int n = in_sizes[0] / 512;   // 100000
    const int E = in_sizes[1] / 2;     // 3200000

    char* ws = (char*)d_ws;
    size_t off = 0;
    auto alloc = [&](size_t bytes) {
        void* p = ws + off;
        off += (bytes + 255) & ~(size_t)255;
        return p;
    };

    const size_t sz_n4  = (size_t)n * 4;
    const size_t sz_hs  = (size_t)n * 16 * 4;
    const size_t REQ_CSR =
        4 * ((sz_n4 + 255 + 4) & ~(size_t)255) + 4096 +
        ((size_t)E * 4) + 2 * sz_hs + 4096;

    const int nb = (n + NTHREADS - 1) / NTHREADS;  // 391 (fits scan_partials' 512)
    const int nodeblocks = (n + 15) / 16;

    if (ws_size == 0 || ws_size >= REQ_CSR) {
        // ---------------- CSR path ----------------
        int*   indeg   = (int*)alloc(sz_n4);
        int*   cnt     = (int*)alloc(sz_n4);
        float* dinv    = (float*)alloc(sz_n4);
        int*   rowptr  = (int*)alloc(sz_n4 + 4);
        int*   partial = (int*)alloc(4096);
        int*   adj     = (int*)alloc((size_t)E * 4);
        float* hs1     = (float*)alloc(sz_hs);
        float* hs2     = (float*)alloc(sz_hs);

        hipMemsetAsync(indeg, 0, sz_n4, stream);
        hipMemsetAsync(cnt, 0, sz_n4, stream);

        hist_kernel<<<4096, NTHREADS, 0, stream>>>(ei + E, E, n, indeg);
        dinv_kernel<<<nb, NTHREADS, 0, stream>>>(indeg, dinv, n);
        scan_block_sums<<<nb, NTHREADS, 0, stream>>>(indeg, partial, n);
        scan_partials<<<1, 512, 0, stream>>>(partial, nb, rowptr, n, E);
        scan_write<<<nb, NTHREADS, 0, stream>>>(indeg, partial, rowptr, n);
        fill_kernel<<<8192, NTHREADS, 0, stream>>>(ei, E, n, rowptr, cnt, adj);

        gemm1_kernel<<<nb, NTHREADS, 0, stream>>>(x, W1, dinv, hs1, n);
        agg1_kernel<<<nodeblocks, NTHREADS, 0, stream>>>(hs1, rowptr, adj, dinv,
                                                         b1, W2, hs2, n);
        agg2_kernel<<<nodeblocks, NTHREADS, 0, stream>>>(hs2, rowptr, adj, dinv,
                                                         b2, Wl, bl, out, n);
    } else {
        // ---------------- Atomic fallback path (~13.6 MB) ----------------
        int*   indeg = (int*)alloc(sz_n4);
        float* dinv  = (float*)alloc(sz_n4);
        float* hs1   = (float*)alloc(sz_hs);
        float* hs2   = (float*)alloc(sz_hs);

        hipMemsetAsync(indeg, 0, sz_n4, stream);
        hist_kernel<<<4096, NTHREADS, 0, stream>>>(ei + E, E, n, indeg);
        dinv_kernel<<<nb, NTHREADS, 0, stream>>>(indeg, dinv, n);

        gemm1_kernel<<<nb, NTHREADS, 0, stream>>>(x, W1, dinv, hs1, n);

        hipMemcpyAsync(hs2, hs1, sz_hs, hipMemcpyDeviceToDevice, stream);
        scatter16_kernel<<<4096, NTHREADS, 0, stream>>>(hs1, hs2, ei, E, n);
        xform1_kernel<<<nodeblocks, NTHREADS, 0, stream>>>(hs2, dinv, b1, W2, n);

        hipMemcpyAsync(hs1, hs2, sz_hs, hipMemcpyDeviceToDevice, stream);
        scatter16_kernel<<<4096, NTHREADS, 0, stream>>>(hs2, hs1, ei, E, n);
        xform2_kernel<<<nodeblocks, NTHREADS, 0, stream>>>(hs1, dinv, b2, Wl,
                                                           bl, out, n);
    }
}